// Round 3
// baseline (314.491 us; speedup 1.0000x reference)
//
#include <hip/hip_runtime.h>
#include <math.h>
#include <stdint.h>

// Problem constants (fixed by reference setup_inputs)
#define BB 8
#define CC 512
#define TT 1024          // H*W
#define NG 32
#define CPG 16
static constexpr float EPS = 1e-5f;
static constexpr float QSCALE = 0.35355339059327373f; // dh^-0.25, folded into Q

typedef __attribute__((ext_vector_type(4))) float f32x4;
typedef __attribute__((ext_vector_type(8))) short s16x8;   // 8 bf16 = 4 VGPRs (guide §3)

// ---------------- bf16 split helpers (x = hi + lo, each bf16, RNE) ----------
__device__ __forceinline__ unsigned short bf16_hi(float x) {
    union { float f; unsigned u; } c; c.f = x;
    unsigned r = c.u + 0x7FFFu + ((c.u >> 16) & 1u);
    return (unsigned short)(r >> 16);
}
__device__ __forceinline__ float bf16_f(unsigned short h) {
    union { unsigned u; float f; } c; c.u = ((unsigned)h) << 16;
    return c.f;
}
__device__ __forceinline__ void split2(float x, unsigned short& h, unsigned short& l) {
    h = bf16_hi(x);
    l = bf16_hi(x - bf16_f(h));
}

// x3 MFMA: D += Ah*Bh + Ah*Bl + Al*Bh  (lo*lo term ~2^-18, dropped)
__device__ __forceinline__ f32x4 mfma3(s16x8 ah, s16x8 al, s16x8 bh, s16x8 bl, f32x4 c) {
    c = __builtin_amdgcn_mfma_f32_16x16x32_bf16(ah, bh, c, 0, 0, 0);
    c = __builtin_amdgcn_mfma_f32_16x16x32_bf16(ah, bl, c, 0, 0, 0);
    c = __builtin_amdgcn_mfma_f32_16x16x32_bf16(al, bh, c, 0, 0, 0);
    return c;
}

// LDS chunk swizzles (chunk = 16B slot index within a 128B row; both sides use
// the same involution so write/read agree; spreads lanes uniformly over banks)
__device__ __forceinline__ int kswz(int row, int ch) { return ch ^ (row & 7); }
__device__ __forceinline__ int pswz(int row, int ch) { return ch ^ (((row >> 2) & 3) << 1); }

// ---------------------------------------------------------------------------
// 1) GroupNorm stats: one block per (b,g)
__global__ __launch_bounds__(256) void gn_stats_kernel(const float* __restrict__ x,
                                                       float* __restrict__ stats) {
    int bg = blockIdx.x;
    const float* base = x + (size_t)bg * (CPG * TT);
    float s = 0.f, ss = 0.f;
    for (int f = threadIdx.x; f < (CPG * TT) / 4; f += 256) {
        float4 v = *(const float4*)(base + 4 * f);
        s  += v.x + v.y + v.z + v.w;
        ss += v.x * v.x + v.y * v.y + v.z * v.z + v.w * v.w;
    }
    for (int off = 32; off; off >>= 1) {
        s  += __shfl_down(s, off);
        ss += __shfl_down(ss, off);
    }
    __shared__ float rs[4], rss[4];
    int wid = threadIdx.x >> 6, lane = threadIdx.x & 63;
    if (lane == 0) { rs[wid] = s; rss[wid] = ss; }
    __syncthreads();
    if (threadIdx.x == 0) {
        float S = rs[0] + rs[1] + rs[2] + rs[3];
        float SS = rss[0] + rss[1] + rss[2] + rss[3];
        const float invN = 1.f / (CPG * TT);
        float mu = S * invN;
        float var = SS * invN - mu * mu;
        stats[bg * 2]     = mu;
        stats[bg * 2 + 1] = rsqrtf(var + EPS);
    }
}

// ---------------------------------------------------------------------------
// 2) GN apply + transpose -> X hi/lo bf16 planes [B*T, C]
__global__ __launch_bounds__(256) void gn_apply_kernel(const float* __restrict__ x,
                                                       const float* __restrict__ stats,
                                                       const float* __restrict__ gamma,
                                                       const float* __restrict__ beta,
                                                       unsigned short* __restrict__ xh,
                                                       unsigned short* __restrict__ xl) {
    __shared__ float tile[32][33];
    int c0 = blockIdx.x << 5, t0 = blockIdx.y << 5, b = blockIdx.z;
    int tx = threadIdx.x, ty = threadIdx.y;   // block (32,8)
#pragma unroll
    for (int k = 0; k < 32; k += 8) {
        int c = c0 + ty + k;
        float mu   = stats[(b * NG + (c >> 4)) * 2];
        float rstd = stats[(b * NG + (c >> 4)) * 2 + 1];
        float v = x[((size_t)(b * CC + c)) * TT + t0 + tx];
        tile[ty + k][tx] = (v - mu) * rstd * gamma[c] + beta[c];
    }
    __syncthreads();
#pragma unroll
    for (int k = 0; k < 32; k += 8) {
        int t = t0 + ty + k;
        float v = tile[tx][ty + k];
        size_t idx = ((size_t)(b * TT + t)) * CC + c0 + tx;
        unsigned short h, l; split2(v, h, l);
        xh[idx] = h; xl[idx] = l;
    }
}

// ---------------------------------------------------------------------------
// 3) Split weights -> hi/lo planes (wq,wk,wv,wo concatenated)
__global__ __launch_bounds__(256) void wsplit_kernel(const float* __restrict__ wq,
                                                     const float* __restrict__ wk,
                                                     const float* __restrict__ wv,
                                                     const float* __restrict__ wo,
                                                     unsigned short* __restrict__ wh,
                                                     unsigned short* __restrict__ wl) {
    int wid = blockIdx.y;
    const float* src = (wid == 0) ? wq : (wid == 1) ? wk : (wid == 2) ? wv : wo;
    int base = (blockIdx.x * 256 + threadIdx.x) * 8;   // 128*256*8 = 262144
    float4 a = *(const float4*)(src + base);
    float4 b = *(const float4*)(src + base + 4);
    float v[8] = {a.x, a.y, a.z, a.w, b.x, b.y, b.z, b.w};
    s16x8 h, l;
#pragma unroll
    for (int i = 0; i < 8; ++i) {
        unsigned short hh, ll; split2(v[i], hh, ll);
        h[i] = (short)hh; l[i] = (short)ll;
    }
    *(s16x8*)(wh + (size_t)wid * 262144 + base) = h;
    *(s16x8*)(wl + (size_t)wid * 262144 + base) = l;
}

// ---------------------------------------------------------------------------
// 4) x3-MFMA GEMM mainloop: 128x128 tile, 4 waves (2x2), wave tile 64x64,
//    BK=32. LDS row = 128B (hi chunks 0-3 | lo chunks 4-7), kswz swizzle.
__device__ __forceinline__ void gemm_main(const unsigned short* __restrict__ ah,
                                          const unsigned short* __restrict__ al,
                                          const unsigned short* __restrict__ wh,
                                          const unsigned short* __restrict__ wl,
                                          int i0, int j0, f32x4 (&acc)[4][4]) {
    __shared__ unsigned short As[128 * 64], Bs[128 * 64];   // 16 KB each
    int tid = threadIdx.x;
    int lane = tid & 63, wv = tid >> 6;
    int lr = lane & 15, lg = lane >> 4;
    int wr = wv >> 1, wc = wv & 1;
    const f32x4 z4 = {0.f, 0.f, 0.f, 0.f};
#pragma unroll
    for (int m = 0; m < 4; ++m)
#pragma unroll
        for (int n = 0; n < 4; ++n) acc[m][n] = z4;

    for (int k0 = 0; k0 < 512; k0 += 32) {
        __syncthreads();   // protect previous iteration's reads
#pragma unroll
        for (int u = 0; u < 4; ++u) {
            int f = u * 256 + tid;           // 0..1023
            int row = f >> 3, s = f & 7;     // row 0..127, logical chunk 0..7
            int pl = s >> 2, ck = s & 3;     // plane, k-chunk(8 bf16)
            const unsigned short* asrc = (pl ? al : ah) + (size_t)(i0 + row) * 512 + k0 + ck * 8;
            const unsigned short* bsrc = (pl ? wl : wh) + (size_t)(j0 + row) * 512 + k0 + ck * 8;
            int d = row * 64 + (kswz(row, s) << 3);
            *(s16x8*)&As[d] = *(const s16x8*)asrc;
            *(s16x8*)&Bs[d] = *(const s16x8*)bsrc;
        }
        __syncthreads();

        s16x8 aH[4], aL[4], bH[4], bL[4];
#pragma unroll
        for (int m = 0; m < 4; ++m) {
            int row = wr * 64 + m * 16 + lr;
            aH[m] = *(const s16x8*)&As[row * 64 + (kswz(row, lg) << 3)];
            aL[m] = *(const s16x8*)&As[row * 64 + (kswz(row, lg + 4) << 3)];
        }
#pragma unroll
        for (int n = 0; n < 4; ++n) {
            int row = wc * 64 + n * 16 + lr;
            bH[n] = *(const s16x8*)&Bs[row * 64 + (kswz(row, lg) << 3)];
            bL[n] = *(const s16x8*)&Bs[row * 64 + (kswz(row, lg + 4) << 3)];
        }
#pragma unroll
        for (int m = 0; m < 4; ++m)
#pragma unroll
            for (int n = 0; n < 4; ++n)
                acc[m][n] = mfma3(aH[m], aL[m], bH[n], bL[n], acc[m][n]);
    }
}

// QKV: z selects weight/bias; output -> Q/K/V hi,lo planes [B*NH, T, 64],
// QSCALE folded into Q.
__global__ __launch_bounds__(256) void qkv_gemm_kernel(
        const unsigned short* __restrict__ xh, const unsigned short* __restrict__ xl,
        const unsigned short* __restrict__ whA, const unsigned short* __restrict__ wlA,
        const float* __restrict__ bq, const float* __restrict__ bk, const float* __restrict__ bv,
        unsigned short* qh, unsigned short* ql, unsigned short* kh, unsigned short* kl,
        unsigned short* vh, unsigned short* vl) {
    int z = blockIdx.z;
    const unsigned short* wh = whA + (size_t)z * 262144;
    const unsigned short* wl = wlA + (size_t)z * 262144;
    const float* bias = (z == 0) ? bq : (z == 1) ? bk : bv;
    unsigned short* dh = (z == 0) ? qh : (z == 1) ? kh : vh;
    unsigned short* dl = (z == 0) ? ql : (z == 1) ? kl : vl;
    float scale = (z == 0) ? QSCALE : 1.f;
    int j0 = blockIdx.x << 7, i0 = blockIdx.y << 7;
    f32x4 acc[4][4];
    gemm_main(xh, xl, wh, wl, i0, j0, acc);
    int tid = threadIdx.x, lane = tid & 63, wv = tid >> 6;
    int lr = lane & 15, lg = lane >> 4, wr = wv >> 1, wc = wv & 1;
#pragma unroll
    for (int n = 0; n < 4; ++n) {
        int j = j0 + wc * 64 + n * 16 + lr;
        float bj = bias[j];
#pragma unroll
        for (int m = 0; m < 4; ++m)
#pragma unroll
            for (int r = 0; r < 4; ++r) {
                int i = i0 + wr * 64 + m * 16 + lg * 4 + r;       // b*1024 + t
                float v = (acc[m][n][r] + bj) * scale;
                size_t off = (((size_t)(i >> 10) * 8 + (j >> 6)) << 16)
                             + (size_t)(i & 1023) * 64 + (j & 63);
                unsigned short hh, ll; split2(v, hh, ll);
                dh[off] = hh; dl[off] = ll;
            }
    }
}

// Output projection: ctx planes -> Y fp32 [8192,512]
__global__ __launch_bounds__(256) void proj_gemm_kernel(
        const unsigned short* __restrict__ ch, const unsigned short* __restrict__ cl,
        const unsigned short* __restrict__ wh, const unsigned short* __restrict__ wl,
        const float* __restrict__ bo, float* __restrict__ Y) {
    int j0 = blockIdx.x << 7, i0 = blockIdx.y << 7;
    f32x4 acc[4][4];
    gemm_main(ch, cl, wh, wl, i0, j0, acc);
    int tid = threadIdx.x, lane = tid & 63, wv = tid >> 6;
    int lr = lane & 15, lg = lane >> 4, wr = wv >> 1, wc = wv & 1;
#pragma unroll
    for (int n = 0; n < 4; ++n) {
        int j = j0 + wc * 64 + n * 16 + lr;
        float bj = bo[j];
#pragma unroll
        for (int m = 0; m < 4; ++m)
#pragma unroll
            for (int r = 0; r < 4; ++r) {
                int i = i0 + wr * 64 + m * 16 + lg * 4 + r;
                Y[(size_t)i * 512 + j] = acc[m][n][r] + bj;
            }
    }
}

// ---------------------------------------------------------------------------
// 5) Flash attention, x3 MFMA. Block = 64 q-rows of one (b,h); 4 waves,
//    wave w owns q-rows w*16..w*16+15. K/V tiles of 64. V transposed in LDS.
__global__ __launch_bounds__(256) void attn_mfma_kernel(
        const unsigned short* __restrict__ qh, const unsigned short* __restrict__ ql,
        const unsigned short* __restrict__ kh, const unsigned short* __restrict__ kl,
        const unsigned short* __restrict__ vh, const unsigned short* __restrict__ vl,
        unsigned short* __restrict__ ch, unsigned short* __restrict__ cl) {
    __shared__ unsigned short Qh[64 * 64], Ql[64 * 64], Kh_[64 * 64], Kl_[64 * 64],
                              Vth[64 * 64], Vtl[64 * 64], Ph[64 * 64], Pl[64 * 64]; // 64 KB
    // XCD-chunked swizzle: all 16 q-tiles of one (b,h) land on one XCD
    int id = blockIdx.x;
    int fid = (id & 7) * 128 + (id >> 3);
    int bh = fid >> 4, qt = fid & 15;
    int tid = threadIdx.x, lane = tid & 63, w = tid >> 6;
    int lr = lane & 15, lg = lane >> 4;
    size_t pbase = (size_t)bh << 16;   // *1024*64

    // stage Q (once)
#pragma unroll
    for (int u = 0; u < 2; ++u) {
        int f = u * 256 + tid;          // 0..511
        int row = f >> 3, s = f & 7;
        int d = row * 64 + (kswz(row, s) << 3);
        size_t g = pbase + (size_t)(qt * 64 + row) * 64 + s * 8;
        *(s16x8*)&Qh[d] = *(const s16x8*)(qh + g);
        *(s16x8*)&Ql[d] = *(const s16x8*)(ql + g);
    }
    float m_[4], l_[4];
    f32x4 o[4];
    const f32x4 z4 = {0.f, 0.f, 0.f, 0.f};
#pragma unroll
    for (int r = 0; r < 4; ++r) { m_[r] = -INFINITY; l_[r] = 0.f; }
#pragma unroll
    for (int n = 0; n < 4; ++n) o[n] = z4;

    for (int kt = 0; kt < 16; ++kt) {
        __syncthreads();   // Q visible (1st) / protect K,V overwrite (later)
        // stage K tile
#pragma unroll
        for (int u = 0; u < 2; ++u) {
            int f = u * 256 + tid;
            int row = f >> 3, s = f & 7;
            int d = row * 64 + (kswz(row, s) << 3);
            size_t g = pbase + (size_t)(kt * 64 + row) * 64 + s * 8;
            *(s16x8*)&Kh_[d] = *(const s16x8*)(kh + g);
            *(s16x8*)&Kl_[d] = *(const s16x8*)(kl + g);
        }
        // stage V transposed: Vt[d][t], wave w covers d-group w*16..+15
        {
            int t = lane, dg = w;
            size_t g = pbase + (size_t)(kt * 64 + t) * 64 + dg * 16;
            s16x8 h0 = *(const s16x8*)(vh + g), h1 = *(const s16x8*)(vh + g + 8);
            s16x8 l0 = *(const s16x8*)(vl + g), l1 = *(const s16x8*)(vl + g + 8);
#pragma unroll
            for (int i = 0; i < 8; ++i) {
                int d0 = dg * 16 + i, d1 = dg * 16 + 8 + i;
                int o0 = d0 * 64 + (kswz(d0, t >> 3) << 3) + (t & 7);
                int o1 = d1 * 64 + (kswz(d1, t >> 3) << 3) + (t & 7);
                Vth[o0] = (unsigned short)h0[i]; Vth[o1] = (unsigned short)h1[i];
                Vtl[o0] = (unsigned short)l0[i]; Vtl[o1] = (unsigned short)l1[i];
            }
        }
        __syncthreads();

        // S = Q K^T  (wave: 16 q x 64 keys = 4 n-frags, D=64 -> 2 k-chunks)
        f32x4 s4[4];
#pragma unroll
        for (int n = 0; n < 4; ++n) s4[n] = z4;
#pragma unroll
        for (int c = 0; c < 2; ++c) {
            int arow = w * 16 + lr;
            s16x8 aH = *(const s16x8*)&Qh[arow * 64 + (kswz(arow, lg + 4 * c) << 3)];
            s16x8 aL = *(const s16x8*)&Ql[arow * 64 + (kswz(arow, lg + 4 * c) << 3)];
#pragma unroll
            for (int n = 0; n < 4; ++n) {
                int brow = n * 16 + lr;
                s16x8 bH = *(const s16x8*)&Kh_[brow * 64 + (kswz(brow, lg + 4 * c) << 3)];
                s16x8 bL = *(const s16x8*)&Kl_[brow * 64 + (kswz(brow, lg + 4 * c) << 3)];
                s4[n] = mfma3(aH, aL, bH, bL, s4[n]);
            }
        }

        // online softmax; thread's q-rows: lg*4 + r (cols spread over 16 lanes)
        float p[4][4];
#pragma unroll
        for (int r = 0; r < 4; ++r) {
            float rmax = fmaxf(fmaxf(s4[0][r], s4[1][r]), fmaxf(s4[2][r], s4[3][r]));
            rmax = fmaxf(rmax, __shfl_xor(rmax, 1));
            rmax = fmaxf(rmax, __shfl_xor(rmax, 2));
            rmax = fmaxf(rmax, __shfl_xor(rmax, 4));
            rmax = fmaxf(rmax, __shfl_xor(rmax, 8));
            float mnew = fmaxf(m_[r], rmax);
            float corr = __expf(m_[r] - mnew);
            float rsum = 0.f;
#pragma unroll
            for (int n = 0; n < 4; ++n) { p[n][r] = __expf(s4[n][r] - mnew); rsum += p[n][r]; }
            rsum += __shfl_xor(rsum, 1); rsum += __shfl_xor(rsum, 2);
            rsum += __shfl_xor(rsum, 4); rsum += __shfl_xor(rsum, 8);
            l_[r] = l_[r] * corr + rsum;
            m_[r] = mnew;
#pragma unroll
            for (int n = 0; n < 4; ++n) o[n][r] *= corr;
        }

        // P -> LDS hi/lo (wave-private rows; conflict-free pswz)
#pragma unroll
        for (int n = 0; n < 4; ++n)
#pragma unroll
            for (int r = 0; r < 4; ++r) {
                int prow = w * 16 + lg * 4 + r;
                int col = n * 16 + lr;
                int idx = prow * 64 + (pswz(prow, col >> 3) << 3) + (col & 7);
                unsigned short hh, ll; split2(p[n][r], hh, ll);
                Ph[idx] = hh; Pl[idx] = ll;
            }

        // O += P V   (same-wave LDS dep; compiler inserts lgkmcnt waits)
#pragma unroll
        for (int c = 0; c < 2; ++c) {
            int prow = w * 16 + lr;
            int pidx = prow * 64 + (pswz(prow, lg + 4 * c) << 3);
            s16x8 aH = *(const s16x8*)&Ph[pidx];
            s16x8 aL = *(const s16x8*)&Pl[pidx];
#pragma unroll
            for (int n = 0; n < 4; ++n) {
                int vrow = n * 16 + lr;   // d
                int vidx = vrow * 64 + (kswz(vrow, lg + 4 * c) << 3);
                s16x8 bH = *(const s16x8*)&Vth[vidx];
                s16x8 bL = *(const s16x8*)&Vtl[vidx];
                o[n] = mfma3(aH, aL, bH, bL, o[n]);
            }
        }
    }

    // epilogue -> ctx hi/lo planes [B*T, C] (c = h*64 + d)
    int b = bh >> 3, h = bh & 7;
#pragma unroll
    for (int r = 0; r < 4; ++r) {
        float inv = 1.f / l_[r];
        int t = qt * 64 + w * 16 + lg * 4 + r;
#pragma unroll
        for (int n = 0; n < 4; ++n) {
            int d = n * 16 + lr;
            float v = o[n][r] * inv;
            size_t off = ((size_t)(b * TT + t)) * 512 + h * 64 + d;
            unsigned short hh, ll; split2(v, hh, ll);
            ch[off] = hh; cl[off] = ll;
        }
    }
}

// ---------------------------------------------------------------------------
// 6) LayerNorm over C + residual + transpose back to [B,C,H,W]
__global__ __launch_bounds__(256) void ln_res_kernel(const float* __restrict__ Y,
                                                     const float* __restrict__ resid,
                                                     const float* __restrict__ g,
                                                     const float* __restrict__ be,
                                                     float* __restrict__ out) {
    __shared__ float rows[32][516];
    __shared__ float mu_s[32], rs_s[32];
    int t0 = blockIdx.x << 5, b = blockIdx.y;
    int tid = threadIdx.x;
#pragma unroll
    for (int it = 0; it < 16; ++it) {
        int f = it * 256 + tid;
        int r = f >> 7, chn = f & 127;
        *(float4*)&rows[r][chn << 2] =
            *(const float4*)(Y + ((size_t)(b * TT) + t0 + r) * 512 + (chn << 2));
    }
    __syncthreads();
    {
        int r = tid >> 3, sub = tid & 7;
        float s = 0.f, ss = 0.f;
        for (int i = 0; i < 64; ++i) {
            float v = rows[r][sub + (i << 3)];
            s += v; ss += v * v;
        }
#pragma unroll
        for (int off = 1; off < 8; off <<= 1) { s += __shfl_xor(s, off); ss += __shfl_xor(ss, off); }
        if (sub == 0) {
            float mu = s * (1.f / 512.f);
            float var = ss * (1.f / 512.f) - mu * mu;
            mu_s[r] = mu; rs_s[r] = rsqrtf(var + EPS);
        }
    }
    __syncthreads();
    int j = tid & 31, crow = tid >> 5;
    for (int it = 0; it < 64; ++it) {
        int c = it * 8 + crow;
        float v = (rows[j][c] - mu_s[j]) * rs_s[j] * g[c] + be[c];
        size_t oidx = ((size_t)(b * 512) + c) * 1024 + t0 + j;
        out[oidx] = v + resid[oidx];
    }
}

// ---------------------------------------------------------------------------
extern "C" void kernel_launch(void* const* d_in, const int* in_sizes, int n_in,
                              void* d_out, int out_size, void* d_ws, size_t ws_size,
                              hipStream_t stream) {
    const float* x        = (const float*)d_in[0];
    const float* gn_gamma = (const float*)d_in[1];
    const float* gn_beta  = (const float*)d_in[2];
    const float* wq = (const float*)d_in[3];
    const float* bq = (const float*)d_in[4];
    const float* wk = (const float*)d_in[5];
    const float* bk = (const float*)d_in[6];
    const float* wv = (const float*)d_in[7];
    const float* bv = (const float*)d_in[8];
    const float* wo = (const float*)d_in[9];
    const float* bo = (const float*)d_in[10];
    const float* ln_gamma = (const float*)d_in[11];
    const float* ln_beta  = (const float*)d_in[12];
    float* out = (float*)d_out;

    // Workspace layout (bytes), ~52 MB total:
    //  [ 0,16M): X hi/lo planes  -> reused as ctx hi/lo planes after QKV
    //  [16,20M): weight hi/lo planes (4 x 512x512 each)
    //  [20,36M): Q hi/lo planes  -> reused as Y fp32 after attention
    //  [36,52M): K hi/lo planes
    //  [52M+  ): GN stats (2 KB)
    // V hi/lo planes live in d_out (16 MB, dead before ln_res overwrites it).
    char* W = (char*)d_ws;
    unsigned short* Xh  = (unsigned short*)(W);
    unsigned short* Xl  = (unsigned short*)(W + (8ull  << 20));
    unsigned short* WhA = (unsigned short*)(W + (16ull << 20));
    unsigned short* WlA = (unsigned short*)(W + (18ull << 20));
    unsigned short* Qh  = (unsigned short*)(W + (20ull << 20));
    unsigned short* Ql  = (unsigned short*)(W + (28ull << 20));
    unsigned short* Kh  = (unsigned short*)(W + (36ull << 20));
    unsigned short* Kl  = (unsigned short*)(W + (44ull << 20));
    float*          Y   = (float*)         (W + (20ull << 20));  // reuse Q region
    float*        stats = (float*)         (W + (52ull << 20));
    unsigned short* ctxh = Xh;                                   // reuse X region
    unsigned short* ctxl = Xl;
    unsigned short* Vh  = (unsigned short*)d_out;
    unsigned short* Vl  = (unsigned short*)d_out + 4194304;

    gn_stats_kernel<<<dim3(BB * NG), dim3(256), 0, stream>>>(x, stats);
    gn_apply_kernel<<<dim3(CC / 32, TT / 32, BB), dim3(32, 8), 0, stream>>>(
        x, stats, gn_gamma, gn_beta, Xh, Xl);
    wsplit_kernel<<<dim3(128, 4), dim3(256), 0, stream>>>(wq, wk, wv, wo, WhA, WlA);
    qkv_gemm_kernel<<<dim3(4, 64, 3), dim3(256), 0, stream>>>(
        Xh, Xl, WhA, WlA, bq, bk, bv, Qh, Ql, Kh, Kl, Vh, Vl);
    attn_mfma_kernel<<<dim3(1024), dim3(256), 0, stream>>>(
        Qh, Ql, Kh, Kl, Vh, Vl, ctxh, ctxl);
    proj_gemm_kernel<<<dim3(4, 64), dim3(256), 0, stream>>>(
        ctxh, ctxl, WhA + 3ull * 262144, WlA + 3ull * 262144, bo, Y);
    ln_res_kernel<<<dim3(TT / 32, BB), dim3(256), 0, stream>>>(
        Y, x, ln_gamma, ln_beta, out);
}

// Round 5
// 309.639 us; speedup vs baseline: 1.0157x; 1.0157x over previous
//
#include <hip/hip_runtime.h>
#include <math.h>
#include <stdint.h>

// Problem constants (fixed by reference setup_inputs)
#define BB 8
#define CC 512
#define TT 1024          // H*W
#define NG 32
#define CPG 16
static constexpr float EPS = 1e-5f;
static constexpr float QSCALE = 0.35355339059327373f; // dh^-0.25, folded into Q

typedef __attribute__((ext_vector_type(4))) float f32x4;
typedef __attribute__((ext_vector_type(8))) short s16x8;   // 8 bf16 = 4 VGPRs
typedef __attribute__((ext_vector_type(4))) short s16x4;

// ---------------- bf16 split helpers (x = hi + lo, each bf16, RNE) ----------
__device__ __forceinline__ unsigned short bf16_hi(float x) {
    union { float f; unsigned u; } c; c.f = x;
    unsigned r = c.u + 0x7FFFu + ((c.u >> 16) & 1u);
    return (unsigned short)(r >> 16);
}
__device__ __forceinline__ float bf16_f(unsigned short h) {
    union { unsigned u; float f; } c; c.u = ((unsigned)h) << 16;
    return c.f;
}
__device__ __forceinline__ void split2(float x, unsigned short& h, unsigned short& l) {
    h = bf16_hi(x);
    l = bf16_hi(x - bf16_f(h));
}

// x3 MFMA: D += Ah*Bh + Ah*Bl + Al*Bh  (lo*lo term ~2^-18, dropped)
__device__ __forceinline__ f32x4 mfma3(s16x8 ah, s16x8 al, s16x8 bh, s16x8 bl, f32x4 c) {
    c = __builtin_amdgcn_mfma_f32_16x16x32_bf16(ah, bh, c, 0, 0, 0);
    c = __builtin_amdgcn_mfma_f32_16x16x32_bf16(ah, bl, c, 0, 0, 0);
    c = __builtin_amdgcn_mfma_f32_16x16x32_bf16(al, bh, c, 0, 0, 0);
    return c;
}

// Direct global->LDS copy, 16 B per lane. LDS dest = wave-uniform base +
// lane*16 (m97/m104); swizzle is applied on the per-lane GLOBAL source.
__device__ __forceinline__ void gload16(const void* g, void* l) {
    __builtin_amdgcn_global_load_lds((const __attribute__((address_space(1))) void*)g,
                                     (__attribute__((address_space(3))) void*)l,
                                     16, 0, 0);
}

// LDS chunk swizzles (chunk = 16B slot within a row; involutions).
// LDS[row][c] holds logical chunk c ^ (row&7); readers use kswz to locate.
__device__ __forceinline__ int kswz(int row, int ch) { return ch ^ (row & 7); }
__device__ __forceinline__ int pswz(int row, int ch) { return ch ^ (((row >> 2) & 3) << 1); }

// ---------------------------------------------------------------------------
// 1) GroupNorm stats: one block per (b,g)
__global__ __launch_bounds__(256) void gn_stats_kernel(const float* __restrict__ x,
                                                       float* __restrict__ stats) {
    int bg = blockIdx.x;
    const float* base = x + (size_t)bg * (CPG * TT);
    float s = 0.f, ss = 0.f;
    for (int f = threadIdx.x; f < (CPG * TT) / 4; f += 256) {
        float4 v = *(const float4*)(base + 4 * f);
        s  += v.x + v.y + v.z + v.w;
        ss += v.x * v.x + v.y * v.y + v.z * v.z + v.w * v.w;
    }
    for (int off = 32; off; off >>= 1) {
        s  += __shfl_down(s, off);
        ss += __shfl_down(ss, off);
    }
    __shared__ float rs[4], rss[4];
    int wid = threadIdx.x >> 6, lane = threadIdx.x & 63;
    if (lane == 0) { rs[wid] = s; rss[wid] = ss; }
    __syncthreads();
    if (threadIdx.x == 0) {
        float S = rs[0] + rs[1] + rs[2] + rs[3];
        float SS = rss[0] + rss[1] + rss[2] + rss[3];
        const float invN = 1.f / (CPG * TT);
        float mu = S * invN;
        float var = SS * invN - mu * mu;
        stats[bg * 2]     = mu;
        stats[bg * 2 + 1] = rsqrtf(var + EPS);
    }
}

// ---------------------------------------------------------------------------
// 2) GN apply + transpose -> X hi/lo bf16 planes [B*T, C]
__global__ __launch_bounds__(256) void gn_apply_kernel(const float* __restrict__ x,
                                                       const float* __restrict__ stats,
                                                       const float* __restrict__ gamma,
                                                       const float* __restrict__ beta,
                                                       unsigned short* __restrict__ xh,
                                                       unsigned short* __restrict__ xl) {
    __shared__ float tile[32][33];
    int c0 = blockIdx.x << 5, t0 = blockIdx.y << 5, b = blockIdx.z;
    int tx = threadIdx.x, ty = threadIdx.y;   // block (32,8)
#pragma unroll
    for (int k = 0; k < 32; k += 8) {
        int c = c0 + ty + k;
        float mu   = stats[(b * NG + (c >> 4)) * 2];
        float rstd = stats[(b * NG + (c >> 4)) * 2 + 1];
        float v = x[((size_t)(b * CC + c)) * TT + t0 + tx];
        tile[ty + k][tx] = (v - mu) * rstd * gamma[c] + beta[c];
    }
    __syncthreads();
#pragma unroll
    for (int k = 0; k < 32; k += 8) {
        int t = t0 + ty + k;
        float v = tile[tx][ty + k];
        size_t idx = ((size_t)(b * TT + t)) * CC + c0 + tx;
        unsigned short h, l; split2(v, h, l);
        xh[idx] = h; xl[idx] = l;
    }
}

// ---------------------------------------------------------------------------
// 3) Split weights -> hi/lo planes (wq,wk,wv,wo concatenated)
__global__ __launch_bounds__(256) void wsplit_kernel(const float* __restrict__ wq,
                                                     const float* __restrict__ wk,
                                                     const float* __restrict__ wv,
                                                     const float* __restrict__ wo,
                                                     unsigned short* __restrict__ wh,
                                                     unsigned short* __restrict__ wl) {
    int wid = blockIdx.y;
    const float* src = (wid == 0) ? wq : (wid == 1) ? wk : (wid == 2) ? wv : wo;
    int base = (blockIdx.x * 256 + threadIdx.x) * 8;   // 128*256*8 = 262144
    float4 a = *(const float4*)(src + base);
    float4 b = *(const float4*)(src + base + 4);
    float v[8] = {a.x, a.y, a.z, a.w, b.x, b.y, b.z, b.w};
    s16x8 h, l;
#pragma unroll
    for (int i = 0; i < 8; ++i) {
        unsigned short hh, ll; split2(v[i], hh, ll);
        h[i] = (short)hh; l[i] = (short)ll;
    }
    *(s16x8*)(wh + (size_t)wid * 262144 + base) = h;
    *(s16x8*)(wl + (size_t)wid * 262144 + base) = l;
}

// ---------------------------------------------------------------------------
// 4) x3-MFMA GEMM mainloop: 128x128 tile, 4 waves (2x2), wave tile 64x64,
//    BK=32. LDS rows of 64 ushorts (8 chunks: hi k0-3 | lo k0-3), staged via
//    global_load_lds with source-side swizzle (LDS dest linear).
__device__ __forceinline__ void gemm_main(const unsigned short* __restrict__ ah,
                                          const unsigned short* __restrict__ al,
                                          const unsigned short* __restrict__ wh,
                                          const unsigned short* __restrict__ wl,
                                          int i0, int j0, f32x4 (&acc)[4][4]) {
    __shared__ unsigned short As[128 * 64], Bs[128 * 64];   // 16 KB each
    int tid = threadIdx.x;
    int lane = tid & 63, wv = tid >> 6;
    int lr = lane & 15, lg = lane >> 4;
    int wr = wv >> 1, wc = wv & 1;
    const f32x4 z4 = {0.f, 0.f, 0.f, 0.f};
#pragma unroll
    for (int m = 0; m < 4; ++m)
#pragma unroll
        for (int n = 0; n < 4; ++n) acc[m][n] = z4;

    // staging geometry: lane writes LDS[row_base + (lane>>3)][lane&7];
    // row&7 == lane>>3, so source logical chunk s = (lane&7) ^ (lane>>3).
    int l8 = lane >> 3, c8 = lane & 7;
    int s = c8 ^ l8;
    int pl = s >> 2, ck = s & 3;              // plane (hi/lo), k-chunk
    const unsigned short* abase = pl ? al : ah;
    const unsigned short* bbase = pl ? wl : wh;
    const unsigned short* ap[4];
    const unsigned short* bp[4];
    unsigned short* ad[4];
    unsigned short* bd[4];
#pragma unroll
    for (int u = 0; u < 4; ++u) {
        int row = u * 32 + wv * 8 + l8;
        ap[u] = abase + (size_t)(i0 + row) * 512 + ck * 8;
        bp[u] = bbase + (size_t)(j0 + row) * 512 + ck * 8;
        ad[u] = &As[u * 2048 + wv * 512];     // wave-uniform dest base
        bd[u] = &Bs[u * 2048 + wv * 512];
    }

    for (int k0 = 0; k0 < 512; k0 += 32) {
        __syncthreads();   // protect previous iteration's reads
#pragma unroll
        for (int u = 0; u < 4; ++u) {
            gload16(ap[u] + k0, ad[u]);
            gload16(bp[u] + k0, bd[u]);
        }
        __syncthreads();   // drains vmcnt -> LDS contents valid

        s16x8 aH[4], aL[4], bH[4], bL[4];
#pragma unroll
        for (int m = 0; m < 4; ++m) {
            int row = wr * 64 + m * 16 + lr;
            aH[m] = *(const s16x8*)&As[row * 64 + (kswz(row, lg) << 3)];
            aL[m] = *(const s16x8*)&As[row * 64 + (kswz(row, lg + 4) << 3)];
        }
#pragma unroll
        for (int n = 0; n < 4; ++n) {
            int row = wc * 64 + n * 16 + lr;
            bH[n] = *(const s16x8*)&Bs[row * 64 + (kswz(row, lg) << 3)];
            bL[n] = *(const s16x8*)&Bs[row * 64 + (kswz(row, lg + 4) << 3)];
        }
#pragma unroll
        for (int m = 0; m < 4; ++m)
#pragma unroll
            for (int n = 0; n < 4; ++n)
                acc[m][n] = mfma3(aH[m], aL[m], bH[n], bL[n], acc[m][n]);
    }
}

// QKV: z selects weight/bias. Q,K -> planes [bh][t][64] (scalar stores);
// V -> TRANSPOSED planes Vt[bh][d][t] with vectorized 8B stores.
__global__ __launch_bounds__(256) void qkv_gemm_kernel(
        const unsigned short* __restrict__ xh, const unsigned short* __restrict__ xl,
        const unsigned short* __restrict__ whA, const unsigned short* __restrict__ wlA,
        const float* __restrict__ bq, const float* __restrict__ bk, const float* __restrict__ bv,
        unsigned short* qh, unsigned short* ql, unsigned short* kh, unsigned short* kl,
        unsigned short* vth, unsigned short* vtl) {
    int z = blockIdx.z;
    const unsigned short* wh = whA + (size_t)z * 262144;
    const unsigned short* wl = wlA + (size_t)z * 262144;
    const float* bias = (z == 0) ? bq : (z == 1) ? bk : bv;
    int j0 = blockIdx.x << 7, i0 = blockIdx.y << 7;
    f32x4 acc[4][4];
    gemm_main(xh, xl, wh, wl, i0, j0, acc);
    int tid = threadIdx.x, lane = tid & 63, wv = tid >> 6;
    int lr = lane & 15, lg = lane >> 4, wr = wv >> 1, wc = wv & 1;
    if (z == 2) {
        // V^T epilogue: thread's 4 r-values are consecutive t at fixed (bh,d)
#pragma unroll
        for (int n = 0; n < 4; ++n) {
            int j = j0 + wc * 64 + n * 16 + lr;
            int d = j & 63, h = j >> 6;
            float bj = bias[j];
#pragma unroll
            for (int m = 0; m < 4; ++m) {
                int ibase = i0 + wr * 64 + m * 16 + lg * 4;   // t base (4-aligned)
                s16x4 v4h, v4l;
#pragma unroll
                for (int r = 0; r < 4; ++r) {
                    float v = acc[m][n][r] + bj;
                    unsigned short hh, ll; split2(v, hh, ll);
                    v4h[r] = (short)hh; v4l[r] = (short)ll;
                }
                size_t off = (((size_t)((ibase >> 10) * 8 + h)) << 16)
                             + (size_t)d * 1024 + (ibase & 1023);
                *(s16x4*)(vth + off) = v4h;
                *(s16x4*)(vtl + off) = v4l;
            }
        }
    } else {
        unsigned short* dh = (z == 0) ? qh : kh;
        unsigned short* dl = (z == 0) ? ql : kl;
        float scale = (z == 0) ? QSCALE : 1.f;
#pragma unroll
        for (int n = 0; n < 4; ++n) {
            int j = j0 + wc * 64 + n * 16 + lr;
            float bj = bias[j];
#pragma unroll
            for (int m = 0; m < 4; ++m)
#pragma unroll
                for (int r = 0; r < 4; ++r) {
                    int i = i0 + wr * 64 + m * 16 + lg * 4 + r;       // b*1024 + t
                    float v = (acc[m][n][r] + bj) * scale;
                    size_t off = (((size_t)(i >> 10) * 8 + (j >> 6)) << 16)
                                 + (size_t)(i & 1023) * 64 + (j & 63);
                    unsigned short hh, ll; split2(v, hh, ll);
                    dh[off] = hh; dl[off] = ll;
                }
        }
    }
}

// Output projection: ctx planes -> Y fp32 [8192,512]
__global__ __launch_bounds__(256) void proj_gemm_kernel(
        const unsigned short* __restrict__ ch, const unsigned short* __restrict__ cl,
        const unsigned short* __restrict__ wh, const unsigned short* __restrict__ wl,
        const float* __restrict__ bo, float* __restrict__ Y) {
    int j0 = blockIdx.x << 7, i0 = blockIdx.y << 7;
    f32x4 acc[4][4];
    gemm_main(ch, cl, wh, wl, i0, j0, acc);
    int tid = threadIdx.x, lane = tid & 63, wv = tid >> 6;
    int lr = lane & 15, lg = lane >> 4, wr = wv >> 1, wc = wv & 1;
#pragma unroll
    for (int n = 0; n < 4; ++n) {
        int j = j0 + wc * 64 + n * 16 + lr;
        float bj = bo[j];
#pragma unroll
        for (int m = 0; m < 4; ++m)
#pragma unroll
            for (int r = 0; r < 4; ++r) {
                int i = i0 + wr * 64 + m * 16 + lg * 4 + r;
                Y[(size_t)i * 512 + j] = acc[m][n][r] + bj;
            }
    }
}

// ---------------------------------------------------------------------------
// 5) Flash attention: Q in registers, K/Vt staged via global_load_lds
//    (48 KB LDS), P through wave-private LDS rows. 4 waves, wave w owns
//    q-rows w*16..w*16+15.
__global__ __launch_bounds__(256) void attn_mfma_kernel(
        const unsigned short* __restrict__ qh, const unsigned short* __restrict__ ql,
        const unsigned short* __restrict__ kh, const unsigned short* __restrict__ kl,
        const unsigned short* __restrict__ vth, const unsigned short* __restrict__ vtl,
        unsigned short* __restrict__ ch, unsigned short* __restrict__ cl) {
    __shared__ unsigned short Kh[64 * 64], Kl[64 * 64],
                              Vh[64 * 64], Vl[64 * 64],
                              Ph[64 * 64], Pl[64 * 64];     // 48 KB
    // XCD-chunked swizzle: all 16 q-tiles of one (b,h) land on one XCD
    int id = blockIdx.x;
    int fid = (id & 7) * 128 + (id >> 3);
    int bh = fid >> 4, qt = fid & 15;
    int tid = threadIdx.x, lane = tid & 63, w = tid >> 6;
    int lr = lane & 15, lg = lane >> 4;
    const size_t pb = (size_t)bh << 16;      // 64K elements per (b,h) plane

    // Q fragments in registers (QSCALE already folded in at QKV epilogue)
    const unsigned short* qrow = qh + pb + (size_t)(qt * 64 + w * 16 + lr) * 64 + lg * 8;
    const unsigned short* qrol = ql + pb + (size_t)(qt * 64 + w * 16 + lr) * 64 + lg * 8;
    s16x8 qH0 = *(const s16x8*)(qrow);
    s16x8 qH1 = *(const s16x8*)(qrow + 32);
    s16x8 qL0 = *(const s16x8*)(qrol);
    s16x8 qL1 = *(const s16x8*)(qrol + 32);

    // staging geometry: LDS[row][lane&7] <- source chunk (lane&7)^(lane>>3)
    int l8 = lane >> 3, c8 = lane & 7;
    int sch = c8 ^ l8;
    int srow = w * 8 + l8;                    // + v*32

    float m_[4], l_[4];
    f32x4 o[4];
    const f32x4 z4 = {0.f, 0.f, 0.f, 0.f};
#pragma unroll
    for (int r = 0; r < 4; ++r) { m_[r] = -INFINITY; l_[r] = 0.f; }
#pragma unroll
    for (int n = 0; n < 4; ++n) o[n] = z4;

    for (int kt = 0; kt < 16; ++kt) {
        __syncthreads();   // protect previous iteration's fragment reads
#pragma unroll
        for (int v = 0; v < 2; ++v) {
            int row = v * 32 + srow;
            size_t kg = pb + (size_t)(kt * 64 + row) * 64 + sch * 8;
            size_t vg = pb + (size_t)row * 1024 + kt * 64 + sch * 8;
            int db = v * 2048 + w * 512;      // wave-uniform LDS dest base
            gload16(kh + kg, &Kh[db]);
            gload16(kl + kg, &Kl[db]);
            gload16(vth + vg, &Vh[db]);
            gload16(vtl + vg, &Vl[db]);
        }
        __syncthreads();   // drains vmcnt -> LDS contents valid

        // S = Q K^T  (wave: 16 q x 64 keys; D=64 -> 2 k-chunks)
        f32x4 s4[4];
#pragma unroll
        for (int n = 0; n < 4; ++n) s4[n] = z4;
#pragma unroll
        for (int c = 0; c < 2; ++c) {
            s16x8 aH = c ? qH1 : qH0;
            s16x8 aL = c ? qL1 : qL0;
#pragma unroll
            for (int n = 0; n < 4; ++n) {
                int brow = n * 16 + lr;
                int pos = brow * 64 + (((c * 4 + lg) ^ (brow & 7)) << 3);
                s4[n] = mfma3(aH, aL, *(const s16x8*)&Kh[pos], *(const s16x8*)&Kl[pos], s4[n]);
            }
        }

        // online softmax; thread's q-rows: lg*4 + r (cols spread over 16 lanes)
        float p[4][4];
#pragma unroll
        for (int r = 0; r < 4; ++r) {
            float rmax = fmaxf(fmaxf(s4[0][r], s4[1][r]), fmaxf(s4[2][r], s4[3][r]));
            rmax = fmaxf(rmax, __shfl_xor(rmax, 1));
            rmax = fmaxf(rmax, __shfl_xor(rmax, 2));
            rmax = fmaxf(rmax, __shfl_xor(rmax, 4));
            rmax = fmaxf(rmax, __shfl_xor(rmax, 8));
            float mnew = fmaxf(m_[r], rmax);
            float corr = __expf(m_[r] - mnew);
            float rsum = 0.f;
#pragma unroll
            for (int n = 0; n < 4; ++n) { p[n][r] = __expf(s4[n][r] - mnew); rsum += p[n][r]; }
            rsum += __shfl_xor(rsum, 1); rsum += __shfl_xor(rsum, 2);
            rsum += __shfl_xor(rsum, 4); rsum += __shfl_xor(rsum, 8);
            l_[r] = l_[r] * corr + rsum;
            m_[r] = mnew;
#pragma unroll
            for (int n = 0; n < 4; ++n) o[n][r] *= corr;
        }

        // P -> wave-private LDS rows (same-wave readback; no barrier needed)
#pragma unroll
        for (int n = 0; n < 4; ++n)
#pragma unroll
            for (int r = 0; r < 4; ++r) {
                int prow = w * 16 + lg * 4 + r;
                int col = n * 16 + lr;
                int idx = prow * 64 + (pswz(prow, col >> 3) << 3) + (col & 7);
                unsigned short hh, ll; split2(p[n][r], hh, ll);
                Ph[idx] = hh; Pl[idx] = ll;
            }

        // O += P V
#pragma unroll
        for (int c = 0; c < 2; ++c) {
            int prow = w * 16 + lr;
            int pidx = prow * 64 + (pswz(prow, c * 4 + lg) << 3);
            s16x8 aH = *(const s16x8*)&Ph[pidx];
            s16x8 aL = *(const s16x8*)&Pl[pidx];
#pragma unroll
            for (int n = 0; n < 4; ++n) {
                int vrow = n * 16 + lr;   // d
                int vidx = vrow * 64 + (((c * 4 + lg) ^ (vrow & 7)) << 3);
                o[n] = mfma3(aH, aL, *(const s16x8*)&Vh[vidx], *(const s16x8*)&Vl[vidx], o[n]);
            }
        }
    }

    // epilogue -> ctx hi/lo planes [B*T, C] (c = h*64 + d)
    int b = bh >> 3, h = bh & 7;
#pragma unroll
    for (int r = 0; r < 4; ++r) {
        float inv = 1.f / l_[r];
        int t = qt * 64 + w * 16 + lg * 4 + r;
#pragma unroll
        for (int n = 0; n < 4; ++n) {
            int d = n * 16 + lr;
            float v = o[n][r] * inv;
            size_t off = ((size_t)(b * TT + t)) * 512 + h * 64 + d;
            unsigned short hh, ll; split2(v, hh, ll);
            ch[off] = hh; cl[off] = ll;
        }
    }
}

// ---------------------------------------------------------------------------
// 6) LayerNorm over C + residual + transpose back to [B,C,H,W]
__global__ __launch_bounds__(256) void ln_res_kernel(const float* __restrict__ Y,
                                                     const float* __restrict__ resid,
                                                     const float* __restrict__ g,
                                                     const float* __restrict__ be,
                                                     float* __restrict__ out) {
    __shared__ float rows[32][516];
    __shared__ float mu_s[32], rs_s[32];
    int t0 = blockIdx.x << 5, b = blockIdx.y;
    int tid = threadIdx.x;
#pragma unroll
    for (int it = 0; it < 16; ++it) {
        int f = it * 256 + tid;
        int r = f >> 7, chn = f & 127;
        *(float4*)&rows[r][chn << 2] =
            *(const float4*)(Y + ((size_t)(b * TT) + t0 + r) * 512 + (chn << 2));
    }
    __syncthreads();
    {
        int r = tid >> 3, sub = tid & 7;
        float s = 0.f, ss = 0.f;
        for (int i = 0; i < 64; ++i) {
            float v = rows[r][sub + (i << 3)];
            s += v; ss += v * v;
        }
#pragma unroll
        for (int off = 1; off < 8; off <<= 1) { s += __shfl_xor(s, off); ss += __shfl_xor(ss, off); }
        if (sub == 0) {
            float mu = s * (1.f / 512.f);
            float var = ss * (1.f / 512.f) - mu * mu;
            mu_s[r] = mu; rs_s[r] = rsqrtf(var + EPS);
        }
    }
    __syncthreads();
    int j = tid & 31, crow = tid >> 5;
    for (int it = 0; it < 64; ++it) {
        int c = it * 8 + crow;
        float v = (rows[j][c] - mu_s[j]) * rs_s[j] * g[c] + be[c];
        size_t oidx = ((size_t)(b * 512) + c) * 1024 + t0 + j;
        out[oidx] = v + resid[oidx];
    }
}

// ---------------------------------------------------------------------------
extern "C" void kernel_launch(void* const* d_in, const int* in_sizes, int n_in,
                              void* d_out, int out_size, void* d_ws, size_t ws_size,
                              hipStream_t stream) {
    const float* x        = (const float*)d_in[0];
    const float* gn_gamma = (const float*)d_in[1];
    const float* gn_beta  = (const float*)d_in[2];
    const float* wq = (const float*)d_in[3];
    const float* bq = (const float*)d_in[4];
    const float* wk = (const float*)d_in[5];
    const float* bk = (const float*)d_in[6];
    const float* wv = (const float*)d_in[7];
    const float* bv = (const float*)d_in[8];
    const float* wo = (const float*)d_in[9];
    const float* bo = (const float*)d_in[10];
    const float* ln_gamma = (const float*)d_in[11];
    const float* ln_beta  = (const float*)d_in[12];
    float* out = (float*)d_out;

    // Workspace layout (bytes), ~52 MB total:
    //  [ 0,16M): X hi/lo planes  -> reused as ctx hi/lo planes after QKV
    //  [16,20M): weight hi/lo planes (4 x 512x512 each)
    //  [20,36M): Q hi/lo planes  -> reused as Y fp32 after attention
    //  [36,52M): K hi/lo planes
    //  [52M+  ): GN stats (2 KB)
    // V^T hi/lo planes live in d_out (16 MB, dead before ln_res overwrites it).
    char* W = (char*)d_ws;
    unsigned short* Xh  = (unsigned short*)(W);
    unsigned short* Xl  = (unsigned short*)(W + (8ull  << 20));
    unsigned short* WhA = (unsigned short*)(W + (16ull << 20));
    unsigned short* WlA = (unsigned short*)(W + (18ull << 20));
    unsigned short* Qh  = (unsigned short*)(W + (20ull << 20));
    unsigned short* Ql  = (unsigned short*)(W + (28ull << 20));
    unsigned short* Kh  = (unsigned short*)(W + (36ull << 20));
    unsigned short* Kl  = (unsigned short*)(W + (44ull << 20));
    float*          Y   = (float*)         (W + (20ull << 20));  // reuse Q region
    float*        stats = (float*)         (W + (52ull << 20));
    unsigned short* ctxh = Xh;                                   // reuse X region
    unsigned short* ctxl = Xl;
    unsigned short* Vth = (unsigned short*)d_out;
    unsigned short* Vtl = (unsigned short*)d_out + 4194304;

    gn_stats_kernel<<<dim3(BB * NG), dim3(256), 0, stream>>>(x, stats);
    gn_apply_kernel<<<dim3(CC / 32, TT / 32, BB), dim3(32, 8), 0, stream>>>(
        x, stats, gn_gamma, gn_beta, Xh, Xl);
    wsplit_kernel<<<dim3(128, 4), dim3(256), 0, stream>>>(wq, wk, wv, wo, WhA, WlA);
    qkv_gemm_kernel<<<dim3(4, 64, 3), dim3(256), 0, stream>>>(
        Xh, Xl, WhA, WlA, bq, bk, bv, Qh, Ql, Kh, Kl, Vth, Vtl);
    attn_mfma_kernel<<<dim3(1024), dim3(256), 0, stream>>>(
        Qh, Ql, Kh, Kl, Vth, Vtl, ctxh, ctxl);
    proj_gemm_kernel<<<dim3(4, 64), dim3(256), 0, stream>>>(
        ctxh, ctxl, WhA + 3ull * 262144, WlA + 3ull * 262144, bo, Y);
    ln_res_kernel<<<dim3(TT / 32, BB), dim3(256), 0, stream>>>(
        Y, x, ln_gamma, ln_beta, out);
}